// Round 3
// baseline (200.144 us; speedup 1.0000x reference)
//
#include <hip/hip_runtime.h>
#include <hip/hip_bf16.h>

// Problem constants
#define BATCH  8
#define SEQ    2048
#define DMODEL 1024
#define DHEAD  128

typedef __attribute__((ext_vector_type(4))) float f32x4;
typedef __attribute__((ext_vector_type(4))) float f4;
typedef _Float16 f16;
typedef __attribute__((ext_vector_type(8))) _Float16 f16x8;
typedef __attribute__((ext_vector_type(8))) __bf16 bf16x8;

__device__ __forceinline__ unsigned short f2bf(float f) {
    unsigned u = __builtin_bit_cast(unsigned, f);
    u += 0x7fffu + ((u >> 16) & 1u);   // round-to-nearest-even
    return (unsigned short)(u >> 16);
}

#if __has_builtin(__builtin_amdgcn_exp2f)
#define EXP2(x) __builtin_amdgcn_exp2f(x)
#else
#define EXP2(x) exp2f(x)
#endif

__device__ __forceinline__ float fast_rcp(float x) {
#if __has_builtin(__builtin_amdgcn_rcpf)
    return __builtin_amdgcn_rcpf(x);
#else
    return 1.0f / x;
#endif
}

// ---------------------------------------------------------------------------
// Kernel 1: projections with split-f16 precision (f32-grade results).
//   out = x @ W^T computed as (xh+xl)@(Wh+Wl)^T dropping xl*Wl (rel ~2^-22).
// Q,K epilogue: hi/lo f16 pairs (QK^T also runs split-f16).
// V epilogue: bf16 (RANGE matters: P pairs with V in one bf16 MFMA and
//   P can be as small as exp(-60)=8.8e-27 -> underflows f16, fits bf16),
//   transposed Vt[b][d][l].
// BM=64, BN=128, BK=32, 4 waves; wave w owns rows w*16..w*16+15.
// ---------------------------------------------------------------------------
__global__ __launch_bounds__(256) void proj_kernel(
    const float* __restrict__ x, const float* __restrict__ WQ,
    const float* __restrict__ WK, const float* __restrict__ WV,
    f16* __restrict__ Qh, f16* __restrict__ Ql,
    f16* __restrict__ Kh, f16* __restrict__ Kl,
    unsigned short* __restrict__ Vtb)
{
    // stride 40 f16 = 80B: 16B-aligned rows
    __shared__ f16 Ah[64][40],  Al[64][40];
    __shared__ f16 Bh[128][40], Bl[128][40];

    const int tid  = threadIdx.x;
    const int lane = tid & 63;
    const int w    = tid >> 6;
    const int lo   = lane & 15;
    const int hi   = lane >> 4;
    const int m0   = blockIdx.x * 64;
    const int mat  = blockIdx.y;               // 0=Q 1=K 2=V
    const float* W = (mat == 0) ? WQ : (mat == 1) ? WK : WV;

    f32x4 acc[8] = {};

    const int arow = tid >> 2;        // 0..63
    const int acol = (tid & 3) * 8;   // 0,8,16,24
    const int brow = tid >> 1;        // 0..127
    const int bcol = (tid & 1) * 16;  // 0,16

    for (int k0 = 0; k0 < DMODEL; k0 += 32) {
        __syncthreads();
        {   // stage x tile -> hi/lo f16
            const float* src = x + (size_t)(m0 + arow) * DMODEL + k0 + acol;
            f4 v0 = *(const f4*)(src);
            f4 v1 = *(const f4*)(src + 4);
            f16x8 oh, ol;
            #pragma unroll
            for (int j = 0; j < 4; ++j) {
                f16 h0 = (f16)v0[j]; oh[j]     = h0; ol[j]     = (f16)(v0[j] - (float)h0);
                f16 h1 = (f16)v1[j]; oh[j + 4] = h1; ol[j + 4] = (f16)(v1[j] - (float)h1);
            }
            *reinterpret_cast<f16x8*>(&Ah[arow][acol]) = oh;
            *reinterpret_cast<f16x8*>(&Al[arow][acol]) = ol;
        }
        {   // stage W tile -> hi/lo f16
            const float* src = W + (size_t)brow * DMODEL + k0 + bcol;
            #pragma unroll
            for (int half = 0; half < 2; ++half) {
                f4 v0 = *(const f4*)(src + half * 8);
                f4 v1 = *(const f4*)(src + half * 8 + 4);
                f16x8 oh, ol;
                #pragma unroll
                for (int j = 0; j < 4; ++j) {
                    f16 h0 = (f16)v0[j]; oh[j]     = h0; ol[j]     = (f16)(v0[j] - (float)h0);
                    f16 h1 = (f16)v1[j]; oh[j + 4] = h1; ol[j + 4] = (f16)(v1[j] - (float)h1);
                }
                *reinterpret_cast<f16x8*>(&Bh[brow][bcol + half * 8]) = oh;
                *reinterpret_cast<f16x8*>(&Bl[brow][bcol + half * 8]) = ol;
            }
        }
        __syncthreads();
        f16x8 ah = *reinterpret_cast<const f16x8*>(&Ah[w * 16 + lo][hi * 8]);
        f16x8 al = *reinterpret_cast<const f16x8*>(&Al[w * 16 + lo][hi * 8]);
        #pragma unroll
        for (int nt = 0; nt < 8; ++nt) {
            f16x8 bh = *reinterpret_cast<const f16x8*>(&Bh[nt * 16 + lo][hi * 8]);
            f16x8 bl = *reinterpret_cast<const f16x8*>(&Bl[nt * 16 + lo][hi * 8]);
            acc[nt] = __builtin_amdgcn_mfma_f32_16x16x32_f16(ah, bh, acc[nt], 0, 0, 0);
            acc[nt] = __builtin_amdgcn_mfma_f32_16x16x32_f16(ah, bl, acc[nt], 0, 0, 0);
            acc[nt] = __builtin_amdgcn_mfma_f32_16x16x32_f16(al, bh, acc[nt], 0, 0, 0);
        }
    }

    // epilogue: D layout col = lane&15, row = (lane>>4)*4 + r
    const int rbase = w * 16 + hi * 4;
    if (mat < 2) {
        f16* dh = (mat == 0) ? Qh : Kh;
        f16* dl = (mat == 0) ? Ql : Kl;
        #pragma unroll
        for (int nt = 0; nt < 8; ++nt)
            #pragma unroll
            for (int r = 0; r < 4; ++r) {
                int m = m0 + rbase + r;
                int n = nt * 16 + lo;
                float v = acc[nt][r];
                f16 h = (f16)v;
                dh[(size_t)m * DHEAD + n] = h;
                dl[(size_t)m * DHEAD + n] = (f16)(v - (float)h);
            }
    } else {
        #pragma unroll
        for (int nt = 0; nt < 8; ++nt)
            #pragma unroll
            for (int r = 0; r < 4; ++r) {
                int m = m0 + rbase + r;
                int n = nt * 16 + lo;
                int bb = m >> 11, l = m & 2047;
                Vtb[((size_t)bb * DHEAD + n) * SEQ + l] = f2bf(acc[nt][r]);
            }
    }
}

// ---------------------------------------------------------------------------
// Kernel 2: causal tanh-capped attention, rescale-free flash.
// S_cap = 30*tanh(s) <= 30 always -> fixed max 30:
//   P = exp(S_cap - 30) = exp2(-86.5617 / (exp2(2.88539*s) + 1)) in [8.8e-27, 1]
// QK^T split-f16 (3 MFMAs) for f32-grade scores; P,V in bf16 (range!).
// 4 waves over the SAME 16 q-rows; key tiles kt%4 across waves (linear in
// key chunks because there is no online rescale). LDS tree-reduce at end.
// ---------------------------------------------------------------------------
__global__ __launch_bounds__(256) void attn_kernel(
    const f16* __restrict__ Qh, const f16* __restrict__ Ql,
    const f16* __restrict__ Kh, const f16* __restrict__ Kl,
    const unsigned short* __restrict__ Vtb, const int* __restrict__ mask,
    float* __restrict__ out)
{
    __shared__ unsigned short Plds[4][16][40];  // per-wave bf16 P tile, padded
    __shared__ float red[2][64][36];            // cross-wave reduction buffer

    const int tid  = threadIdx.x;
    const int lane = tid & 63;
    const int w    = tid >> 6;
    const int lo   = lane & 15;
    const int hi   = lane >> 4;
    const int b    = blockIdx.y;
    const int q0   = (SEQ / 16 - 1 - (int)blockIdx.x) * 16;  // heavy blocks first

    // Q fragments (hi+lo) live in registers for the whole block
    f16x8 qh[4], ql[4];
    {
        const size_t off = ((size_t)(b * SEQ + q0 + lo)) * DHEAD + hi * 8;
        #pragma unroll
        for (int c = 0; c < 4; ++c) {
            qh[c] = *reinterpret_cast<const f16x8*>(Qh + off + c * 32);
            ql[c] = *reinterpret_cast<const f16x8*>(Ql + off + c * 32);
        }
    }

    f32x4 acc[8] = {};
    float rs[4] = {0.f, 0.f, 0.f, 0.f};

    const int   nkt = q0 / 32 + 1;
    const float c2  = 2.8853900817779268f;   //  2*log2(e)
    const float c1  = -86.561702453337804f;  // -60*log2(e)
    const float isd = 0.08838834764831845f;  // 1/sqrt(128)

    for (int kt = w; kt < nkt; kt += 4) {
        const int k0 = kt * 32;
        #pragma unroll
        for (int h = 0; h < 2; ++h) {
            f32x4 s = {};
            const int key = k0 + h * 16 + lo;
            const size_t koff = ((size_t)(b * SEQ + key)) * DHEAD + hi * 8;
            #pragma unroll
            for (int c = 0; c < 4; ++c) {
                f16x8 kh = *reinterpret_cast<const f16x8*>(Kh + koff + c * 32);
                f16x8 kl = *reinterpret_cast<const f16x8*>(Kl + koff + c * 32);
                s = __builtin_amdgcn_mfma_f32_16x16x32_f16(qh[c], kh, s, 0, 0, 0);
                s = __builtin_amdgcn_mfma_f32_16x16x32_f16(qh[c], kl, s, 0, 0, 0);
                s = __builtin_amdgcn_mfma_f32_16x16x32_f16(ql[c], kh, s, 0, 0, 0);
            }
            const int mk = mask[b * SEQ + key];
            #pragma unroll
            for (int r = 0; r < 4; ++r) {
                const int q = q0 + hi * 4 + r;
                float sv = s[r] * isd;
                float t  = EXP2(sv * c2);             // e^{2s} (inf ok)
                float p  = EXP2(c1 * fast_rcp(t + 1.0f));
                p = (key <= q && mk != 0) ? p : 0.0f; // causal + padding mask
                rs[r] += p;
                Plds[w][hi * 4 + r][h * 16 + lo] = f2bf(p);
            }
        }
        // wave-local LDS write->read ordering (single wave, in-order LDS;
        // the asm pins the compiler + drains lgkm)
        asm volatile("s_waitcnt lgkmcnt(0)" ::: "memory");
        bf16x8 pa = *reinterpret_cast<const bf16x8*>(&Plds[w][lo][hi * 8]);
        const unsigned short* vbase =
            Vtb + ((size_t)b * DHEAD + lo) * SEQ + k0 + hi * 8;
        #pragma unroll
        for (int dt = 0; dt < 8; ++dt) {
            bf16x8 vf = *reinterpret_cast<const bf16x8*>(vbase + (size_t)dt * 16 * SEQ);
            acc[dt] = __builtin_amdgcn_mfma_f32_16x16x32_bf16(pa, vf, acc[dt], 0, 0, 0);
        }
        asm volatile("" ::: "memory");
    }

    // cross-wave tree reduction of acc + rs
    if (w >= 2) {
        float* dst = &red[w - 2][lane][0];
        #pragma unroll
        for (int dt = 0; dt < 8; ++dt)
            #pragma unroll
            for (int r = 0; r < 4; ++r) dst[dt * 4 + r] = acc[dt][r];
        #pragma unroll
        for (int r = 0; r < 4; ++r) dst[32 + r] = rs[r];
    }
    __syncthreads();
    if (w < 2) {
        const float* src = &red[w][lane][0];
        #pragma unroll
        for (int dt = 0; dt < 8; ++dt)
            #pragma unroll
            for (int r = 0; r < 4; ++r) acc[dt][r] += src[dt * 4 + r];
        #pragma unroll
        for (int r = 0; r < 4; ++r) rs[r] += src[32 + r];
    }
    __syncthreads();
    if (w == 1) {
        float* dst = &red[1][lane][0];
        #pragma unroll
        for (int dt = 0; dt < 8; ++dt)
            #pragma unroll
            for (int r = 0; r < 4; ++r) dst[dt * 4 + r] = acc[dt][r];
        #pragma unroll
        for (int r = 0; r < 4; ++r) dst[32 + r] = rs[r];
    }
    __syncthreads();
    if (w == 0) {
        const float* src = &red[1][lane][0];
        #pragma unroll
        for (int dt = 0; dt < 8; ++dt)
            #pragma unroll
            for (int r = 0; r < 4; ++r) acc[dt][r] += src[dt * 4 + r];
        #pragma unroll
        for (int r = 0; r < 4; ++r) {
            float v = rs[r] + src[32 + r];
            v += __shfl_xor(v, 1);
            v += __shfl_xor(v, 2);
            v += __shfl_xor(v, 4);
            v += __shfl_xor(v, 8);
            rs[r] = fast_rcp(v);
        }
        #pragma unroll
        for (int dt = 0; dt < 8; ++dt)
            #pragma unroll
            for (int r = 0; r < 4; ++r) {
                size_t q = (size_t)q0 + hi * 4 + r;
                out[((size_t)b * SEQ + q) * DHEAD + dt * 16 + lo] = acc[dt][r] * rs[r];
            }
    }
}

extern "C" void kernel_launch(void* const* d_in, const int* in_sizes, int n_in,
                              void* d_out, int out_size, void* d_ws, size_t ws_size,
                              hipStream_t stream) {
    const float* x   = (const float*)d_in[0];
    const int*   msk = (const int*)d_in[1];
    const float* WQ  = (const float*)d_in[2];
    const float* WK  = (const float*)d_in[3];
    const float* WV  = (const float*)d_in[4];
    float* out = (float*)d_out;

    // workspace: Qh|Ql|Kh|Kl (f16) | Vt (bf16), each B*L*128*2B = 4MB -> 20MB
    const size_t NE = (size_t)BATCH * SEQ * DHEAD;
    f16* Qh = (f16*)d_ws;
    f16* Ql = Qh + NE;
    f16* Kh = Ql + NE;
    f16* Kl = Kh + NE;
    unsigned short* Vtb = (unsigned short*)(Kl + NE);

    proj_kernel<<<dim3(BATCH * SEQ / 64, 3), 256, 0, stream>>>(x, WQ, WK, WV, Qh, Ql, Kh, Kl, Vtb);
    attn_kernel<<<dim3(SEQ / 16, BATCH), 256, 0, stream>>>(Qh, Ql, Kh, Kl, Vtb, msk, out);
}

// Round 4
// 154.670 us; speedup vs baseline: 1.2940x; 1.2940x over previous
//
#include <hip/hip_runtime.h>
#include <hip/hip_bf16.h>

// Problem constants
#define BATCH  8
#define SEQ    2048
#define DMODEL 1024
#define DHEAD  128

typedef __attribute__((ext_vector_type(4))) float f32x4;
typedef __attribute__((ext_vector_type(4))) float f4;
typedef _Float16 f16;
typedef __attribute__((ext_vector_type(8))) _Float16 f16x8;
typedef __attribute__((ext_vector_type(8))) __bf16 bf16x8;

__device__ __forceinline__ unsigned short f2bf(float f) {
    unsigned u = __builtin_bit_cast(unsigned, f);
    u += 0x7fffu + ((u >> 16) & 1u);   // round-to-nearest-even
    return (unsigned short)(u >> 16);
}

#if __has_builtin(__builtin_amdgcn_exp2f)
#define EXP2(x) __builtin_amdgcn_exp2f(x)
#else
#define EXP2(x) exp2f(x)
#endif

__device__ __forceinline__ float fast_rcp(float x) {
#if __has_builtin(__builtin_amdgcn_rcpf)
    return __builtin_amdgcn_rcpf(x);
#else
    return 1.0f / x;
#endif
}

// ---------------------------------------------------------------------------
// Kernel 1: projections. Q,K in split-f16 (f32-grade, 3 MFMAs: scores need
// absolute precision ~0.01 because tanh transition lives at |s|~3 while raw
// scores have std ~1024). V in single-f16 MFMA -> bf16 store (output-grade:
// delta ~0.03 abs; bf16 chosen for RANGE since P in [8.8e-27,1] pairs with V).
// BM=64, BN=128, BK=32, 4 waves.
// ---------------------------------------------------------------------------
__global__ __launch_bounds__(256) void proj_kernel(
    const float* __restrict__ x, const float* __restrict__ WQ,
    const float* __restrict__ WK, const float* __restrict__ WV,
    f16* __restrict__ Qh, f16* __restrict__ Ql,
    f16* __restrict__ Kh, f16* __restrict__ Kl,
    unsigned short* __restrict__ Vtb)
{
    // stride 40 f16 = 80B: 16B-aligned rows
    __shared__ f16 Ah[64][40],  Al[64][40];
    __shared__ f16 Bh[128][40], Bl[128][40];

    const int tid  = threadIdx.x;
    const int lane = tid & 63;
    const int w    = tid >> 6;
    const int lo   = lane & 15;
    const int hi   = lane >> 4;
    const int m0   = blockIdx.x * 64;
    const int mat  = blockIdx.y;               // 0=Q 1=K 2=V
    const float* W = (mat == 0) ? WQ : (mat == 1) ? WK : WV;
    const bool split = (mat < 2);

    f32x4 acc[8] = {};

    const int arow = tid >> 2;        // 0..63
    const int acol = (tid & 3) * 8;   // 0,8,16,24
    const int brow = tid >> 1;        // 0..127
    const int bcol = (tid & 1) * 16;  // 0,16

    for (int k0 = 0; k0 < DMODEL; k0 += 32) {
        __syncthreads();
        {   // stage x tile -> hi (and lo if split)
            const float* src = x + (size_t)(m0 + arow) * DMODEL + k0 + acol;
            f4 v0 = *(const f4*)(src);
            f4 v1 = *(const f4*)(src + 4);
            f16x8 oh, ol;
            #pragma unroll
            for (int j = 0; j < 4; ++j) {
                f16 h0 = (f16)v0[j]; oh[j]     = h0; ol[j]     = (f16)(v0[j] - (float)h0);
                f16 h1 = (f16)v1[j]; oh[j + 4] = h1; ol[j + 4] = (f16)(v1[j] - (float)h1);
            }
            *reinterpret_cast<f16x8*>(&Ah[arow][acol]) = oh;
            if (split) *reinterpret_cast<f16x8*>(&Al[arow][acol]) = ol;
        }
        {   // stage W tile -> hi (and lo if split)
            const float* src = W + (size_t)brow * DMODEL + k0 + bcol;
            #pragma unroll
            for (int halfc = 0; halfc < 2; ++halfc) {
                f4 v0 = *(const f4*)(src + halfc * 8);
                f4 v1 = *(const f4*)(src + halfc * 8 + 4);
                f16x8 oh, ol;
                #pragma unroll
                for (int j = 0; j < 4; ++j) {
                    f16 h0 = (f16)v0[j]; oh[j]     = h0; ol[j]     = (f16)(v0[j] - (float)h0);
                    f16 h1 = (f16)v1[j]; oh[j + 4] = h1; ol[j + 4] = (f16)(v1[j] - (float)h1);
                }
                *reinterpret_cast<f16x8*>(&Bh[brow][bcol + halfc * 8]) = oh;
                if (split) *reinterpret_cast<f16x8*>(&Bl[brow][bcol + halfc * 8]) = ol;
            }
        }
        __syncthreads();
        f16x8 ah = *reinterpret_cast<const f16x8*>(&Ah[w * 16 + lo][hi * 8]);
        if (split) {
            f16x8 al = *reinterpret_cast<const f16x8*>(&Al[w * 16 + lo][hi * 8]);
            #pragma unroll
            for (int nt = 0; nt < 8; ++nt) {
                f16x8 bh = *reinterpret_cast<const f16x8*>(&Bh[nt * 16 + lo][hi * 8]);
                f16x8 bl = *reinterpret_cast<const f16x8*>(&Bl[nt * 16 + lo][hi * 8]);
                acc[nt] = __builtin_amdgcn_mfma_f32_16x16x32_f16(ah, bh, acc[nt], 0, 0, 0);
                acc[nt] = __builtin_amdgcn_mfma_f32_16x16x32_f16(ah, bl, acc[nt], 0, 0, 0);
                acc[nt] = __builtin_amdgcn_mfma_f32_16x16x32_f16(al, bh, acc[nt], 0, 0, 0);
            }
        } else {
            #pragma unroll
            for (int nt = 0; nt < 8; ++nt) {
                f16x8 bh = *reinterpret_cast<const f16x8*>(&Bh[nt * 16 + lo][hi * 8]);
                acc[nt] = __builtin_amdgcn_mfma_f32_16x16x32_f16(ah, bh, acc[nt], 0, 0, 0);
            }
        }
    }

    // epilogue: D layout col = lane&15, row = (lane>>4)*4 + r
    const int rbase = w * 16 + hi * 4;
    if (mat < 2) {
        f16* dh = (mat == 0) ? Qh : Kh;
        f16* dl = (mat == 0) ? Ql : Kl;
        #pragma unroll
        for (int nt = 0; nt < 8; ++nt)
            #pragma unroll
            for (int r = 0; r < 4; ++r) {
                int m = m0 + rbase + r;
                int n = nt * 16 + lo;
                float v = acc[nt][r];
                f16 h = (f16)v;
                dh[(size_t)m * DHEAD + n] = h;
                dl[(size_t)m * DHEAD + n] = (f16)(v - (float)h);
            }
    } else {
        #pragma unroll
        for (int nt = 0; nt < 8; ++nt)
            #pragma unroll
            for (int r = 0; r < 4; ++r) {
                int m = m0 + rbase + r;
                int n = nt * 16 + lo;
                int bb = m >> 11, l = m & 2047;
                Vtb[((size_t)bb * DHEAD + n) * SEQ + l] = f2bf(acc[nt][r]);
            }
    }
}

// ---------------------------------------------------------------------------
// Kernel 2: causal tanh-capped attention, rescale-free flash.
// S_cap = 30*tanh(s) <= 30 -> fixed max 30:
//   P = exp(S_cap-30) = exp2(-86.5617 / (exp2(0.2551*s_raw) + 1)) in [8.8e-27,1]
// QK^T split-f16 (3 MFMAs); P,V bf16 (range). 4 waves share 16 q-rows,
// key tiles kt%4 across waves (linear: no online rescale). Tree-reduce at end.
// Balance: block handles q-tile pair {p, 127-p} -> uniform ~65 iters/block.
// Latency: V + K + mask loads all issued at iteration top (V is
// score-independent); no fences, compiler pipelines across iterations.
// ---------------------------------------------------------------------------
__global__ __launch_bounds__(256, 2) void attn_kernel(
    const f16* __restrict__ Qh, const f16* __restrict__ Ql,
    const f16* __restrict__ Kh, const f16* __restrict__ Kl,
    const unsigned short* __restrict__ Vtb, const int* __restrict__ mask,
    float* __restrict__ out)
{
    __shared__ unsigned short Plds[4][16][40];  // per-wave bf16 P tile, padded
    __shared__ float red[2][64][36];            // cross-wave reduction buffer

    const int tid  = threadIdx.x;
    const int lane = tid & 63;
    const int w    = tid >> 6;
    const int lo   = lane & 15;
    const int hi   = lane >> 4;
    const int b    = blockIdx.y;

    const float c2p = 0.25506061907448296f;   // (2*log2e)/sqrt(128)
    const float c1  = -86.561702453337804f;   // -60*log2e

    #pragma unroll 1
    for (int halfb = 0; halfb < 2; ++halfb) {
        const int qt  = halfb ? 127 - (int)blockIdx.x : (int)blockIdx.x;
        const int q0  = qt * 16;
        const int nkt = qt / 2 + 1;           // == q0/32 + 1

        // Q fragments (hi+lo) in registers for the whole tile
        f16x8 qh[4], ql[4];
        {
            const size_t off = ((size_t)(b * SEQ + q0 + lo)) * DHEAD + hi * 8;
            #pragma unroll
            for (int c = 0; c < 4; ++c) {
                qh[c] = *reinterpret_cast<const f16x8*>(Qh + off + c * 32);
                ql[c] = *reinterpret_cast<const f16x8*>(Ql + off + c * 32);
            }
        }

        f32x4 acc[8] = {};
        float rs[4] = {0.f, 0.f, 0.f, 0.f};

        for (int kt = w; kt < nkt; kt += 4) {
            const int k0 = kt * 32;

            // ---- early issue: V (consumed last), K both halves, masks ----
            bf16x8 vf[8];
            const unsigned short* vbase =
                Vtb + ((size_t)b * DHEAD + lo) * SEQ + k0 + hi * 8;
            #pragma unroll
            for (int dt = 0; dt < 8; ++dt)
                vf[dt] = *reinterpret_cast<const bf16x8*>(vbase + (size_t)dt * 16 * SEQ);

            f16x8 kh[2][4], kl[2][4];
            int mk[2];
            #pragma unroll
            for (int h = 0; h < 2; ++h) {
                const int key = k0 + h * 16 + lo;
                const size_t koff = ((size_t)(b * SEQ + key)) * DHEAD + hi * 8;
                #pragma unroll
                for (int c = 0; c < 4; ++c) {
                    kh[h][c] = *reinterpret_cast<const f16x8*>(Kh + koff + c * 32);
                    kl[h][c] = *reinterpret_cast<const f16x8*>(Kl + koff + c * 32);
                }
                mk[h] = mask[b * SEQ + key];
            }

            // ---- QK^T + softmax per 16-key half ----
            #pragma unroll
            for (int h = 0; h < 2; ++h) {
                f32x4 s = {};
                #pragma unroll
                for (int c = 0; c < 4; ++c) {
                    s = __builtin_amdgcn_mfma_f32_16x16x32_f16(qh[c], kh[h][c], s, 0, 0, 0);
                    s = __builtin_amdgcn_mfma_f32_16x16x32_f16(qh[c], kl[h][c], s, 0, 0, 0);
                    s = __builtin_amdgcn_mfma_f32_16x16x32_f16(ql[c], kh[h][c], s, 0, 0, 0);
                }
                const int key = k0 + h * 16 + lo;
                #pragma unroll
                for (int r = 0; r < 4; ++r) {
                    const int q = q0 + hi * 4 + r;
                    float t = EXP2(s[r] * c2p);               // e^{2s} (inf ok)
                    float p = EXP2(c1 * fast_rcp(t + 1.0f));
                    p = (key <= q && mk[h] != 0) ? p : 0.0f;  // causal + padding
                    rs[r] += p;
                    Plds[w][hi * 4 + r][h * 16 + lo] = f2bf(p);
                }
            }

            // P transpose via per-wave LDS (compiler inserts lgkmcnt)
            bf16x8 pa = *reinterpret_cast<const bf16x8*>(&Plds[w][lo][hi * 8]);
            #pragma unroll
            for (int dt = 0; dt < 8; ++dt)
                acc[dt] = __builtin_amdgcn_mfma_f32_16x16x32_bf16(pa, vf[dt], acc[dt], 0, 0, 0);
        }

        // ---- cross-wave tree reduction of acc + rs ----
        if (w >= 2) {
            float* dst = &red[w - 2][lane][0];
            #pragma unroll
            for (int dt = 0; dt < 8; ++dt)
                #pragma unroll
                for (int r = 0; r < 4; ++r) dst[dt * 4 + r] = acc[dt][r];
            #pragma unroll
            for (int r = 0; r < 4; ++r) dst[32 + r] = rs[r];
        }
        __syncthreads();
        if (w < 2) {
            const float* src = &red[w][lane][0];
            #pragma unroll
            for (int dt = 0; dt < 8; ++dt)
                #pragma unroll
                for (int r = 0; r < 4; ++r) acc[dt][r] += src[dt * 4 + r];
            #pragma unroll
            for (int r = 0; r < 4; ++r) rs[r] += src[32 + r];
        }
        __syncthreads();
        if (w == 1) {
            float* dst = &red[1][lane][0];
            #pragma unroll
            for (int dt = 0; dt < 8; ++dt)
                #pragma unroll
                for (int r = 0; r < 4; ++r) dst[dt * 4 + r] = acc[dt][r];
            #pragma unroll
            for (int r = 0; r < 4; ++r) dst[32 + r] = rs[r];
        }
        __syncthreads();
        if (w == 0) {
            const float* src = &red[1][lane][0];
            #pragma unroll
            for (int dt = 0; dt < 8; ++dt)
                #pragma unroll
                for (int r = 0; r < 4; ++r) acc[dt][r] += src[dt * 4 + r];
            #pragma unroll
            for (int r = 0; r < 4; ++r) {
                float v = rs[r] + src[32 + r];
                v += __shfl_xor(v, 1);
                v += __shfl_xor(v, 2);
                v += __shfl_xor(v, 4);
                v += __shfl_xor(v, 8);
                rs[r] = fast_rcp(v);
            }
            #pragma unroll
            for (int dt = 0; dt < 8; ++dt)
                #pragma unroll
                for (int r = 0; r < 4; ++r) {
                    size_t q = (size_t)q0 + hi * 4 + r;
                    out[((size_t)b * SEQ + q) * DHEAD + dt * 16 + lo] = acc[dt][r] * rs[r];
                }
        }
        __syncthreads();   // release red/Plds for the paired tile
    }
}

extern "C" void kernel_launch(void* const* d_in, const int* in_sizes, int n_in,
                              void* d_out, int out_size, void* d_ws, size_t ws_size,
                              hipStream_t stream) {
    const float* x   = (const float*)d_in[0];
    const int*   msk = (const int*)d_in[1];
    const float* WQ  = (const float*)d_in[2];
    const float* WK  = (const float*)d_in[3];
    const float* WV  = (const float*)d_in[4];
    float* out = (float*)d_out;

    // workspace: Qh|Ql|Kh|Kl (f16) | Vt (bf16), each B*L*128*2B = 4MB -> 20MB
    const size_t NE = (size_t)BATCH * SEQ * DHEAD;
    f16* Qh = (f16*)d_ws;
    f16* Ql = Qh + NE;
    f16* Kh = Ql + NE;
    f16* Kl = Kh + NE;
    unsigned short* Vtb = (unsigned short*)(Kl + NE);

    proj_kernel<<<dim3(BATCH * SEQ / 64, 3), 256, 0, stream>>>(x, WQ, WK, WV, Qh, Ql, Kh, Kl, Vtb);
    attn_kernel<<<dim3(64, BATCH), 256, 0, stream>>>(Qh, Ql, Kh, Kl, Vtb, msk, out);
}